// Round 2
// baseline (484.529 us; speedup 1.0000x reference)
//
#include <hip/hip_runtime.h>
#include <stdint.h>

// SymmetricContraction (MACE) on MI355X. All I/O float32 (per reference).
// Design: block = (part, e, c). y is one-hot, so per-node weights depend only
// on element e -> precompute combined tables in LDS:
//   c3[m,j,l,i] = sum_k U3[m,i,j,l,k] * W3[e,k,c]
//   c2[m,j,l]   = sum_k U2[m,j,l,k]   * W2[e,k,c]
//   c1[m,j]     = sum_k U1[m,j,k]     * W1[e,k,c]
// then per node (thread <-> node, LDS broadcast reads, fp32 math):
//   out[m] = sum_j x_j (sum_l x_l (sum_i x_i c3 + c2) + c1)

#define BN 2048
#define CN 128
#define IN_ 16
#define EN 10

template <int M, int K3, int K2, int OUTBASE>
__global__ __launch_bounds__(256, 2) void sc_kernel(
    const float* __restrict__ xg,   // [B, C, 16]
    const float* __restrict__ yg,   // [B, E] one-hot
    const float* __restrict__ U3,   // [M, 16, 16, 16, K3]
    const float* __restrict__ U2,   // [M, 16, 16, K2]
    const float* __restrict__ U1,   // [M, 16, 1]
    const float* __restrict__ W3,   // [E, K3, C]
    const float* __restrict__ W2,   // [E, K2, C]
    const float* __restrict__ W1,   // [E, 1, C]
    float* __restrict__ outg)       // [B, 512]
{
    const int c = blockIdx.x;
    const int e = blockIdx.y;
    const int tid = threadIdx.x;

    __shared__ float c3s[M * 16 * 16 * 16];  // [m][j][l][i]
    __shared__ float c2s[M * 16 * 16];       // [m][j][l]
    __shared__ float c1s[M * 16];            // [m][j]
    __shared__ float wk3s[K3];
    __shared__ float wk2s[K2];
    __shared__ float wk1s[1];
    __shared__ int nodelist[BN];
    __shared__ int ncount;

    if (tid == 0) ncount = 0;
    if (tid < K3) wk3s[tid] = W3[(e * K3 + tid) * CN + c];
    if (tid >= 64 && tid < 64 + K2) wk2s[tid - 64] = W2[(e * K2 + (tid - 64)) * CN + c];
    if (tid == 96) wk1s[0] = W1[e * CN + c];
    __syncthreads();

    // --- build node list for element e (y is exactly one-hot) ---
    for (int b = tid; b < BN; b += 256) {
        if (yg[b * EN + e] > 0.5f) {
            int p = atomicAdd(&ncount, 1);
            nodelist[p] = b;
        }
    }

    // --- build c3 table: enumerate (m,i,j,l) in U3 order for coalesced reads ---
    for (int idx = tid; idx < M * 4096; idx += 256) {
        const int l = idx & 15;
        const int j = (idx >> 4) & 15;
        const int m = idx >> 12;
        const float* up = U3 + (size_t)idx * K3;
        float acc = 0.f;
#pragma unroll
        for (int k = 0; k < K3; ++k) acc = fmaf(up[k], wk3s[k], acc);
        const int i = (idx >> 8) & 15;
        c3s[((m * 16 + j) * 16 + l) * 16 + i] = acc;
    }
    // --- c2 table: enumeration (m,j,l) matches both U2 and LDS layout ---
    for (int idx = tid; idx < M * 256; idx += 256) {
        const float* up = U2 + (size_t)idx * K2;
        float acc = 0.f;
#pragma unroll
        for (int k = 0; k < K2; ++k) acc = fmaf(up[k], wk2s[k], acc);
        c2s[idx] = acc;
    }
    // --- c1 (K1 == 1) ---
    if (tid < M * 16) c1s[tid] = U1[tid] * wk1s[0];
    __syncthreads();

    const int cnt = ncount;
    for (int s = tid; s < cnt; s += 256) {
        const int n = nodelist[s];
        const float* xp = xg + ((size_t)n * CN + c) * IN_;

        // load x[n,c,0:16] (64B, 64B-aligned)
        float xr[16];
        {
            const float4 a0 = ((const float4*)xp)[0];
            const float4 a1 = ((const float4*)xp)[1];
            const float4 a2 = ((const float4*)xp)[2];
            const float4 a3 = ((const float4*)xp)[3];
            xr[0] = a0.x; xr[1] = a0.y; xr[2] = a0.z; xr[3] = a0.w;
            xr[4] = a1.x; xr[5] = a1.y; xr[6] = a1.z; xr[7] = a1.w;
            xr[8] = a2.x; xr[9] = a2.y; xr[10] = a2.z; xr[11] = a2.w;
            xr[12] = a3.x; xr[13] = a3.y; xr[14] = a3.z; xr[15] = a3.w;
        }

#pragma unroll 1
        for (int m = 0; m < M; ++m) {
            float fm = 0.f;
#pragma unroll 1
            for (int j = 0; j < 16; ++j) {
                const int mj = m * 16 + j;
                float bj = 0.f;
#pragma unroll
                for (int l = 0; l < 16; ++l) {
                    const float4* row = (const float4*)(c3s + (mj * 16 + l) * 16);
                    const float4 r0 = row[0];
                    const float4 r1 = row[1];
                    const float4 r2 = row[2];
                    const float4 r3 = row[3];
                    float a = c2s[mj * 16 + l];
                    a = fmaf(r0.x, xr[0], a);
                    a = fmaf(r0.y, xr[1], a);
                    a = fmaf(r0.z, xr[2], a);
                    a = fmaf(r0.w, xr[3], a);
                    a = fmaf(r1.x, xr[4], a);
                    a = fmaf(r1.y, xr[5], a);
                    a = fmaf(r1.z, xr[6], a);
                    a = fmaf(r1.w, xr[7], a);
                    a = fmaf(r2.x, xr[8], a);
                    a = fmaf(r2.y, xr[9], a);
                    a = fmaf(r2.z, xr[10], a);
                    a = fmaf(r2.w, xr[11], a);
                    a = fmaf(r3.x, xr[12], a);
                    a = fmaf(r3.y, xr[13], a);
                    a = fmaf(r3.z, xr[14], a);
                    a = fmaf(r3.w, xr[15], a);
                    bj = fmaf(a, xr[l], bj);
                }
                bj += c1s[mj];
                fm = fmaf(bj, xp[j], fm);  // x_j reload: L1-hot, avoids dyn reg index
            }
            outg[(size_t)n * 512 + OUTBASE + c * M + m] = fm;
        }
    }
}

extern "C" void kernel_launch(void* const* d_in, const int* in_sizes, int n_in,
                              void* d_out, int out_size, void* d_ws, size_t ws_size,
                              hipStream_t stream) {
    const float* x = (const float*)d_in[0];
    const float* y = (const float*)d_in[1];
    const float* U3_0 = (const float*)d_in[2];
    const float* U2_0 = (const float*)d_in[3];
    const float* U1_0 = (const float*)d_in[4];
    const float* W3_0 = (const float*)d_in[5];
    const float* W2_0 = (const float*)d_in[6];
    const float* W1_0 = (const float*)d_in[7];
    const float* U3_1 = (const float*)d_in[8];
    const float* U2_1 = (const float*)d_in[9];
    const float* U1_1 = (const float*)d_in[10];
    const float* W3_1 = (const float*)d_in[11];
    const float* W2_1 = (const float*)d_in[12];
    const float* W1_1 = (const float*)d_in[13];
    float* out = (float*)d_out;

    dim3 grid(CN, EN);
    // part 0 (0e): M=1, K3=23, K2=4 -> out cols [0,128)
    sc_kernel<1, 23, 4, 0><<<grid, 256, 0, stream>>>(x, y, U3_0, U2_0, U1_0, W3_0, W2_0, W1_0, out);
    // part 1 (1o): M=3, K3=33, K2=5 -> out cols [128,512), col = 128 + c*3 + m
    sc_kernel<3, 33, 5, 128><<<grid, 256, 0, stream>>>(x, y, U3_1, U2_1, U1_1, W3_1, W2_1, W1_1, out);
}